// Round 8
// baseline (1655.749 us; speedup 1.0000x reference)
//
#include <hip/hip_runtime.h>
#include <math.h>

#define M_TOK 1024   // B*S
#define DM    2048   // d_model
#define NH    256    // heads
#define HD    8      // head dim
#define SCALE 0.35355339059327373f   // 1/sqrt(8)

typedef _Float16 f16x8 __attribute__((ext_vector_type(8)));
typedef _Float16 f16x4 __attribute__((ext_vector_type(4)));
typedef float    f32x4 __attribute__((ext_vector_type(4)));
typedef float    f32x16 __attribute__((ext_vector_type(16)));

// ---------------------------------------------------------------------------
// prep: z<4 -> weight fp32 [k][n] -> fp16 [n][k] (cast+transpose, 64x64 tiles);
//       z==4 -> x fp32 -> fp16 cast into MFMA-A-FRAGMENT-MAJOR layout
//       (frag f=(m>>5)*128+(k>>4), lane=(m&31)+32*((k>>3)&1) -> contiguous 1KB
//       per wave A-fragment load in the GEMM).
__global__ __launch_bounds__(256) void prep(
    const float* __restrict__ x, _Float16* __restrict__ xh,
    const float* __restrict__ W0, const float* __restrict__ W1,
    const float* __restrict__ W2, const float* __restrict__ W3,
    _Float16* __restrict__ T0, _Float16* __restrict__ T1,
    _Float16* __restrict__ T2, _Float16* __restrict__ T3)
{
    __shared__ float t[64][65];
    const int tid = threadIdx.x;
    const int z   = blockIdx.z;

    if (z == 4) {   // cast x -> fragment-major
        const int i  = (blockIdx.y * 32 + blockIdx.x) * 256 + tid;   // < 262144
        const int m  = i >> 8;
        const int k0 = (i & 255) * 8;
        const float4 a = ((const float4*)x)[2 * i];
        const float4 b = ((const float4*)x)[2 * i + 1];
        f16x8 v;
        v[0] = (_Float16)a.x; v[1] = (_Float16)a.y; v[2] = (_Float16)a.z; v[3] = (_Float16)a.w;
        v[4] = (_Float16)b.x; v[5] = (_Float16)b.y; v[6] = (_Float16)b.z; v[7] = (_Float16)b.w;
        const int f    = (m >> 5) * 128 + (k0 >> 4);
        const int lane = (m & 31) + ((k0 >> 3) & 1) * 32;
        ((f16x8*)xh)[f * 64 + lane] = v;
        return;
    }

    const float* W = (z == 0) ? W0 : (z == 1) ? W1 : (z == 2) ? W2 : W3;
    _Float16*    T = (z == 0) ? T0 : (z == 1) ? T1 : (z == 2) ? T2 : T3;

    const int nb = blockIdx.x * 64;
    const int kb = blockIdx.y * 64;
    const int tr = tid >> 4;
    const int tc = (tid & 15) << 2;

    #pragma unroll
    for (int rr = 0; rr < 4; ++rr) {
        const int k = kb + rr * 16 + tr;
        const float4 v = *(const float4*)&W[(size_t)k * DM + nb + tc];
        t[rr * 16 + tr][tc + 0] = v.x;
        t[rr * 16 + tr][tc + 1] = v.y;
        t[rr * 16 + tr][tc + 2] = v.z;
        t[rr * 16 + tr][tc + 3] = v.w;
    }
    __syncthreads();
    #pragma unroll
    for (int rr = 0; rr < 4; ++rr) {
        const int n = nb + rr * 16 + tr;
        f16x4 v;
        #pragma unroll
        for (int j = 0; j < 4; ++j)
            v[j] = (_Float16)t[tc + j][rr * 16 + tr];
        *(f16x4*)&T[(size_t)n * DM + kb + tc] = v;
    }
}

// ---------------------------------------------------------------------------
// QKV GEMM: 128x128 tile, BK=64, mfma_f32_32x32x16_f16, 4 waves in 2x2,
// wave-tile 64x64. A direct-from-global (fragment-major, reg prefetch
// distance 2). B staged TWO-STEP: global->VGPR (distance 2)->ds_write into
// XOR-swizzled dbuf LDS. Barrier drains only short-lived ops; in-flight
// global loads for tile k+2 have ~1.5 iterations to land.
// Layouts identical to R7 (bench-verified).
__global__ __launch_bounds__(256, 2) void gemm_qkv32(
    const _Float16* __restrict__ A,   // fragment-major xa
    const _Float16* __restrict__ Bt0, const float* __restrict__ b0, _Float16* __restrict__ C0,
    const _Float16* __restrict__ Bt1, const float* __restrict__ b1, _Float16* __restrict__ C1,
    const _Float16* __restrict__ Bt2, const float* __restrict__ b2, _Float16* __restrict__ C2)
{
    __shared__ _Float16 Bs[2][128 * 64];   // 32 KB total

    const int which = blockIdx.x >> 4;
    const int bn    = (blockIdx.x & 15) * 128;
    const int bm    = blockIdx.y * 128;

    const _Float16* Bt   = (which == 0) ? Bt0 : (which == 1) ? Bt1 : Bt2;
    const float*    bias = (which == 0) ? b0  : (which == 1) ? b1  : b2;
    _Float16*       C    = (which == 0) ? C0  : (which == 1) ? C1  : C2;

    const int tid  = threadIdx.x;
    const int lane = tid & 63;
    const int wv   = tid >> 6;          // 0..3
    const int wrow = wv >> 1;
    const int wcol = wv & 1;
    const int l31  = lane & 31;
    const int lk   = lane >> 5;
    const int R0   = blockIdx.y * 4 + wrow * 2;   // row-block-of-32 index

    // B staging addresses (R7 pattern): wave wv covers rows [wv*32, wv*32+32)
    const _Float16* gB[4];
    int             lB[4];
    #pragma unroll
    for (int p = 0; p < 4; ++p) {
        const int r = wv * 32 + p * 8 + (lane >> 3);
        const int c = (lane & 7) ^ ((lane >> 3) & 7);
        gB[p] = Bt + (size_t)(bn + r) * DM + c * 8;
        lB[p] = (wv * 4 + p) * 512 + lane * 8;
    }

    f32x16 acc[2][2] = {};
    f16x8  aR[2][2][4];   // [set][mt][ks]
    f16x8  bR[2][4];      // [set][p]

    auto loadB = [&](int s, int kt) {
        #pragma unroll
        for (int p = 0; p < 4; ++p)
            bR[s][p] = *(const f16x8*)(gB[p] + kt * 64);
    };
    auto writeB = [&](int buf, int s) {
        #pragma unroll
        for (int p = 0; p < 4; ++p)
            *(f16x8*)&Bs[buf][lB[p]] = bR[s][p];
    };
    auto loadA = [&](int s, int kt) {
        #pragma unroll
        for (int mt = 0; mt < 2; ++mt) {
            const _Float16* base = A + ((size_t)(R0 + mt) * 128 + kt * 4) * 512 + lane * 8;
            #pragma unroll
            for (int ks = 0; ks < 4; ++ks)
                aR[s][mt][ks] = *(const f16x8*)(base + ks * 512);
        }
    };
    auto compute = [&](int buf, int s) {
        #pragma unroll
        for (int ks = 0; ks < 4; ++ks) {
            f16x8 bF[2];
            #pragma unroll
            for (int nt = 0; nt < 2; ++nt) {
                const int n = wcol * 64 + nt * 32 + l31;
                const int c = ks * 2 + lk;
                bF[nt] = *(const f16x8*)&Bs[buf][n * 64 + (c ^ (n & 7)) * 8];
            }
            #pragma unroll
            for (int mt = 0; mt < 2; ++mt)
                #pragma unroll
                for (int nt = 0; nt < 2; ++nt)
                    acc[mt][nt] = __builtin_amdgcn_mfma_f32_32x32x16_f16(
                        aR[s][mt][ks], bF[nt], acc[mt][nt], 0, 0, 0);
        }
    };

    // prologue: tiles 0,1 into reg sets; tile 0 into LDS buf0
    loadB(0, 0); loadA(0, 0);
    loadB(1, 1); loadA(1, 1);
    writeB(0, 0);
    __syncthreads();

    #pragma unroll 1
    for (int k = 0; k < 32; ++k) {
        const int cur = k & 1, nxt = cur ^ 1;
        writeB(nxt, nxt);                 // tile k+1 -> Bs[nxt] (regs loaded >=1 iter ago)
        compute(cur, cur);                // tile k from Bs[cur] + aR[cur]
        if (k < 30) { loadB(cur, k + 2); loadA(cur, k + 2); }   // refill freed sets
        __syncthreads();                  // Bs[nxt] visible; Bs[cur] reads done
    }

    // epilogue: 32x32 C/D: col=lane&31, row=(reg&3)+8*(reg>>2)+4*(lane>>5)
    #pragma unroll
    for (int mt = 0; mt < 2; ++mt) {
        #pragma unroll
        for (int nt = 0; nt < 2; ++nt) {
            const int col = bn + wcol * 64 + nt * 32 + l31;
            const float bv = bias[col];
            const int rbase = bm + wrow * 64 + mt * 32 + 4 * lk;
            #pragma unroll
            for (int r = 0; r < 16; ++r) {
                const int row = rbase + (r & 3) + 8 * (r >> 2);
                C[(size_t)row * DM + col] = (_Float16)(acc[mt][nt][r] + bv);
            }
        }
    }
}

// ---------------------------------------------------------------------------
// Double-buffered 16x16 MFMA GEMM (O-projection), two-step staging:
// global->VGPR (distance 2)->ds_write, XOR-swizzled LDS, 1 barrier/K-tile.
template<int WGR, int WGC, int WTR, int WTC, bool F16OUT>
__global__ __launch_bounds__(256, 3) void gemm_db(
    const _Float16* __restrict__ A,
    const _Float16* __restrict__ Bt0, const float* __restrict__ b0, void* __restrict__ C0,
    const _Float16* __restrict__ Bt1, const float* __restrict__ b1, void* __restrict__ C1,
    const _Float16* __restrict__ Bt2, const float* __restrict__ b2, void* __restrict__ C2)
{
    constexpr int BM  = WGR * WTR * 16;
    constexpr int BN  = WGC * WTC * 16;
    static_assert(BN == 128, "col tile must be 128");
    constexpr int NA  = BM / 8;
    constexpr int NB  = 16;
    constexpr int NC  = NA + NB;
    constexpr int CPW = NC / 4;
    static_assert(NC % 4 == 0);
    constexpr int BUF = (BM + 128) * 64;

    __shared__ _Float16 smem[2 * BUF];

    const int which = blockIdx.x >> 4;
    const int bn    = (blockIdx.x & 15) * 128;
    const int bm    = blockIdx.y * BM;

    const _Float16* Bt   = (which == 0) ? Bt0 : (which == 1) ? Bt1 : Bt2;
    const float*    bias = (which == 0) ? b0  : (which == 1) ? b1  : b2;
    void*           C    = (which == 0) ? C0  : (which == 1) ? C1  : C2;

    const int tid  = threadIdx.x;
    const int lane = tid & 63;
    const int wv   = tid >> 6;
    const int wr   = (wv / WGC) * (WTR * 16);
    const int wc   = (wv % WGC) * (WTC * 16);
    const int lr   = lane & 15;
    const int lk   = lane >> 4;
    const int rx   = lr & 7;

    const _Float16* gsrc[CPW];
    int             loff[CPW];
    #pragma unroll
    for (int p = 0; p < CPW; ++p) {
        const int c   = wv * CPW + p;
        const int kch = ((lane & 7) ^ (lane >> 3)) << 3;
        if (c < NA) {
            const int rl = c * 8 + (lane >> 3);
            gsrc[p] = A + (size_t)(bm + rl) * DM + kch;
            loff[p] = c * 512 + lane * 8;
        } else {
            const int rl = (c - NA) * 8 + (lane >> 3);
            gsrc[p] = Bt + (size_t)(bn + rl) * DM + kch;
            loff[p] = BM * 64 + (c - NA) * 512 + lane * 8;
        }
    }

    int offA[WTR][2], offB[WTC][2];
    #pragma unroll
    for (int ks = 0; ks < 2; ++ks) {
        const int sw = (((ks << 2) | lk) ^ rx) << 3;
        #pragma unroll
        for (int i = 0; i < WTR; ++i)
            offA[i][ks] = (wr + i * 16 + lr) * 64 + sw;
        #pragma unroll
        for (int j = 0; j < WTC; ++j)
            offB[j][ks] = BM * 64 + (wc + j * 16 + lr) * 64 + sw;
    }

    f32x4 acc[WTR][WTC] = {};
    f16x8 rS[2][CPW];

    auto loadR = [&](int s, int kt) {
        #pragma unroll
        for (int p = 0; p < CPW; ++p)
            rS[s][p] = *(const f16x8*)(gsrc[p] + kt * 64);
    };
    auto writeS = [&](int buf, int s) {
        #pragma unroll
        for (int p = 0; p < CPW; ++p)
            *(f16x8*)(smem + buf * BUF + loff[p]) = rS[s][p];
    };
    auto compute = [&](int buf) {
        const _Float16* base = smem + buf * BUF;
        #pragma unroll
        for (int ks = 0; ks < 2; ++ks) {
            f16x8 aF[WTR], bF[WTC];
            #pragma unroll
            for (int i = 0; i < WTR; ++i)
                aF[i] = *(const f16x8*)&base[offA[i][ks]];
            #pragma unroll
            for (int j = 0; j < WTC; ++j)
                bF[j] = *(const f16x8*)&base[offB[j][ks]];
            #pragma unroll
            for (int i = 0; i < WTR; ++i)
                #pragma unroll
                for (int j = 0; j < WTC; ++j)
                    acc[i][j] = __builtin_amdgcn_mfma_f32_16x16x32_f16(aF[i], bF[j], acc[i][j], 0, 0, 0);
        }
    };

    loadR(0, 0);
    loadR(1, 1);
    writeS(0, 0);
    __syncthreads();

    #pragma unroll 1
    for (int k = 0; k < 32; ++k) {
        const int cur = k & 1, nxt = cur ^ 1;
        writeS(nxt, nxt);                 // tile k+1
        compute(cur);                     // tile k
        if (k < 30) loadR(cur, k + 2);    // tile k+2 into freed set
        __syncthreads();
    }

    #pragma unroll
    for (int i = 0; i < WTR; ++i) {
        #pragma unroll
        for (int j = 0; j < WTC; ++j) {
            const int col = bn + wc + j * 16 + lr;
            const float bv = bias[col];
            #pragma unroll
            for (int r = 0; r < 4; ++r) {
                const int row = bm + wr + i * 16 + lk * 4 + r;
                const float v = acc[i][j][r] + bv;
                if (F16OUT)
                    ((_Float16*)C)[(size_t)row * DM + col] = (_Float16)v;
                else
                    ((float*)C)[(size_t)row * DM + col] = v;
            }
        }
    }
}

// ---------------------------------------------------------------------------
// MFMA attention: one block per token, 4 waves, wave wv owns heads
// [64wv, 64wv+64). S^T = K.Q^T via mfma (K=8 zero-padded), exp in fp32,
// pack to fp16 in LDS (wave-private region, no barrier), O = A.V via mfma.
__global__ __launch_bounds__(256) void attn_mfma(
    const _Float16* __restrict__ Qh, const _Float16* __restrict__ Kh,
    const _Float16* __restrict__ Vh, _Float16* __restrict__ Oh)
{
    __shared__ _Float16 Vt[8][264];
    __shared__ _Float16 Al[256][72];
    __shared__ _Float16 Ot[256][8];

    const int t    = blockIdx.x;
    const int tid  = threadIdx.x;
    const int lane = tid & 63;
    const int wv   = tid >> 6;
    const int col  = lane & 15;
    const int quad = lane >> 4;
    const int hbase = wv * 64;

    const _Float16* qb = Qh + (size_t)t * DM;
    const _Float16* kb = Kh + (size_t)t * DM;
    const _Float16* vb = Vh + (size_t)t * DM;

    {
        const f16x8 v = *(const f16x8*)(vb + tid * 8);
        #pragma unroll
        for (int d = 0; d < 8; ++d) Vt[d][tid] = v[d];
    }

    f16x8 qf[4];
    #pragma unroll
    for (int ht = 0; ht < 4; ++ht) {
        f16x8 v = {};
        if (quad == 0)
            v = *(const f16x8*)(qb + (hbase + ht * 16 + col) * 8);
        #pragma unroll
        for (int j = 0; j < 8; ++j) qf[ht][j] = v[j] * (_Float16)SCALE;
    }

    __syncthreads();

    const f32x4 zf = {};
    float rsum[4] = {};
    f32x4 oacc[4] = {};

    #pragma unroll 1
    for (int c = 0; c < 4; ++c) {
        const int gchunk = c * 64;

        f16x8 kf[4];
        #pragma unroll
        for (int gt = 0; gt < 4; ++gt) {
            f16x8 v = {};
            if (quad == 0)
                v = *(const f16x8*)(kb + (gchunk + gt * 16 + col) * 8);
            kf[gt] = v;
        }

        f32x4 s[4][4];
        #pragma unroll
        for (int gt = 0; gt < 4; ++gt)
            #pragma unroll
            for (int ht = 0; ht < 4; ++ht)
                s[gt][ht] = __builtin_amdgcn_mfma_f32_16x16x32_f16(kf[gt], qf[ht], zf, 0, 0, 0);

        #pragma unroll
        for (int gt = 0; gt < 4; ++gt) {
            #pragma unroll
            for (int ht = 0; ht < 4; ++ht) {
                f16x4 e4;
                #pragma unroll
                for (int r = 0; r < 4; ++r) {
                    e4[r] = (_Float16)__expf(s[gt][ht][r]);
                    rsum[ht] += (float)e4[r];
                }
                *(f16x4*)&Al[hbase + ht * 16 + col][gt * 16 + quad * 4] = e4;
            }
        }

        #pragma unroll
        for (int ks = 0; ks < 2; ++ks) {
            f16x8 vf = {};
            if (col < 8)
                vf = *(const f16x8*)&Vt[col][gchunk + ks * 32 + quad * 8];
            #pragma unroll
            for (int ht = 0; ht < 4; ++ht) {
                const f16x8 af = *(const f16x8*)&Al[hbase + ht * 16 + col][ks * 32 + quad * 8];
                oacc[ht] = __builtin_amdgcn_mfma_f32_16x16x32_f16(af, vf, oacc[ht], 0, 0, 0);
            }
        }
    }

    #pragma unroll
    for (int ht = 0; ht < 4; ++ht) {
        rsum[ht] += __shfl_xor(rsum[ht], 16, 64);
        rsum[ht] += __shfl_xor(rsum[ht], 32, 64);
    }

    #pragma unroll
    for (int ht = 0; ht < 4; ++ht) {
        #pragma unroll
        for (int r = 0; r < 4; ++r) {
            const float sh = __shfl(rsum[ht], quad * 4 + r, 64);
            const float v  = oacc[ht][r] / sh;
            if (col < 8)
                Ot[hbase + ht * 16 + quad * 4 + r][col] = (_Float16)v;
        }
    }
    const f16x8 ov = *(const f16x8*)&Ot[tid][0];
    *(f16x8*)(Oh + (size_t)t * DM + tid * 8) = ov;
}

// ---------------------------------------------------------------------------
extern "C" void kernel_launch(void* const* d_in, const int* in_sizes, int n_in,
                              void* d_out, int out_size, void* d_ws, size_t ws_size,
                              hipStream_t stream)
{
    const float* x  = (const float*)d_in[0];
    // d_in[1] = phase_shift: cancels analytically (cos^2 + sin^2 = 1), unused
    const float* Wq = (const float*)d_in[2];
    const float* bq = (const float*)d_in[3];
    const float* Wk = (const float*)d_in[4];
    const float* bk = (const float*)d_in[5];
    const float* Wv = (const float*)d_in[6];
    const float* bv = (const float*)d_in[7];
    const float* Wo = (const float*)d_in[8];
    const float* bo = (const float*)d_in[9];
    float* out = (float*)d_out;

    char* ws = (char*)d_ws;
    _Float16* xa  = (_Float16*)(ws);                 // 4 MB, fragment-major
    _Float16* Wtq = (_Float16*)(ws + (4u  << 20));   // 8 MB
    _Float16* Wtk = (_Float16*)(ws + (12u << 20));   // 8 MB
    _Float16* Wtv = (_Float16*)(ws + (20u << 20));   // 8 MB
    _Float16* Wto = (_Float16*)(ws + (28u << 20));   // 8 MB
    _Float16* Qh  = (_Float16*)(ws + (36u << 20));   // 4 MB
    _Float16* Kh  = (_Float16*)(ws + (40u << 20));   // 4 MB
    _Float16* Vh  = (_Float16*)(ws + (44u << 20));   // 4 MB
    _Float16* Oh  = (_Float16*)(ws + (48u << 20));   // 4 MB

    prep<<<dim3(32, 32, 5), dim3(256), 0, stream>>>(
        x, xa, Wq, Wk, Wv, Wo, Wtq, Wtk, Wtv, Wto);

    // QKV fused: 128x128 tiles, 32x32x16 mfma, two-step staging. grid 48 x 8
    gemm_qkv32<<<dim3(48, 8), dim3(256), 0, stream>>>(xa,
        Wtq, bq, Qh,
        Wtk, bk, Kh,
        Wtv, bv, Vh);

    attn_mfma<<<dim3(M_TOK), dim3(256), 0, stream>>>(Qh, Kh, Vh, Oh);

    // output projection: 32x128 tiles, BK=64, two-step dbuf. grid 16 x 32
    gemm_db<1, 4, 2, 2, false><<<dim3(16, 32), dim3(256), 0, stream>>>(Oh,
        Wto, bo, (void*)out,
        Wto, bo, (void*)out,
        Wto, bo, (void*)out);
}

// Round 10
// 204.606 us; speedup vs baseline: 8.0924x; 8.0924x over previous
//
#include <hip/hip_runtime.h>
#include <math.h>

#define M_TOK 1024   // B*S
#define DM    2048   // d_model
#define NH    256    // heads
#define HD    8      // head dim
#define SCALE 0.35355339059327373f   // 1/sqrt(8)

typedef _Float16 f16x8 __attribute__((ext_vector_type(8)));
typedef _Float16 f16x4 __attribute__((ext_vector_type(4)));
typedef float    f32x4 __attribute__((ext_vector_type(4)));
typedef float    f32x16 __attribute__((ext_vector_type(16)));

// ---------------------------------------------------------------------------
// prep: z<4 -> weight fp32 [k][n] -> fp16 [n][k] (cast+transpose, 64x64 tiles);
//       z==4 -> x fp32 -> fp16 cast into MFMA-A-FRAGMENT-MAJOR layout
//       (frag f=(m>>5)*128+(k>>4), lane=(m&31)+32*((k>>3)&1) -> contiguous 1KB
//       per wave A-fragment load in the GEMM).  [R7-verbatim, bench-verified]
__global__ __launch_bounds__(256) void prep(
    const float* __restrict__ x, _Float16* __restrict__ xh,
    const float* __restrict__ W0, const float* __restrict__ W1,
    const float* __restrict__ W2, const float* __restrict__ W3,
    _Float16* __restrict__ T0, _Float16* __restrict__ T1,
    _Float16* __restrict__ T2, _Float16* __restrict__ T3)
{
    __shared__ float t[64][65];
    const int tid = threadIdx.x;
    const int z   = blockIdx.z;

    if (z == 4) {   // cast x -> fragment-major
        const int i  = (blockIdx.y * 32 + blockIdx.x) * 256 + tid;   // < 262144
        const int m  = i >> 8;
        const int k0 = (i & 255) * 8;
        const float4 a = ((const float4*)x)[2 * i];
        const float4 b = ((const float4*)x)[2 * i + 1];
        f16x8 v;
        v[0] = (_Float16)a.x; v[1] = (_Float16)a.y; v[2] = (_Float16)a.z; v[3] = (_Float16)a.w;
        v[4] = (_Float16)b.x; v[5] = (_Float16)b.y; v[6] = (_Float16)b.z; v[7] = (_Float16)b.w;
        const int f    = (m >> 5) * 128 + (k0 >> 4);
        const int lane = (m & 31) + ((k0 >> 3) & 1) * 32;
        ((f16x8*)xh)[f * 64 + lane] = v;
        return;
    }

    const float* W = (z == 0) ? W0 : (z == 1) ? W1 : (z == 2) ? W2 : W3;
    _Float16*    T = (z == 0) ? T0 : (z == 1) ? T1 : (z == 2) ? T2 : T3;

    const int nb = blockIdx.x * 64;
    const int kb = blockIdx.y * 64;
    const int tr = tid >> 4;
    const int tc = (tid & 15) << 2;

    #pragma unroll
    for (int rr = 0; rr < 4; ++rr) {
        const int k = kb + rr * 16 + tr;
        const float4 v = *(const float4*)&W[(size_t)k * DM + nb + tc];
        t[rr * 16 + tr][tc + 0] = v.x;
        t[rr * 16 + tr][tc + 1] = v.y;
        t[rr * 16 + tr][tc + 2] = v.z;
        t[rr * 16 + tr][tc + 3] = v.w;
    }
    __syncthreads();
    #pragma unroll
    for (int rr = 0; rr < 4; ++rr) {
        const int n = nb + rr * 16 + tr;
        f16x4 v;
        #pragma unroll
        for (int j = 0; j < 4; ++j)
            v[j] = (_Float16)t[tc + j][rr * 16 + tr];
        *(f16x4*)&T[(size_t)n * DM + kb + tc] = v;
    }
}

// ---------------------------------------------------------------------------
// QKV GEMM: 64x128 tile, BK=64, mfma_f32_32x32x16_f16, 4 waves in 2x2,
// wave-tile 32x64 (2 n-subtiles). Grid 48 x 16 = 768 blocks = 3 blocks/CU.
// A: direct global->reg from fragment-major xa (contiguous 1 KB/wave-load),
//    2 register sets, prefetch distance 1 K-tile.  [R7-verbatim path]
// B: global_load_lds into XOR-swizzled dbuf LDS (2 x 16 KB). [R7-verbatim]
// Control flow identical to R7's loop (bench-verified); only the wave-tile
// m-extent changed (64 -> 32) to double the grid for barrier-drain cover.
__global__ __launch_bounds__(256, 3) void gemm_qkv32(
    const _Float16* __restrict__ A,   // fragment-major xa
    const _Float16* __restrict__ Bt0, const float* __restrict__ b0, _Float16* __restrict__ C0,
    const _Float16* __restrict__ Bt1, const float* __restrict__ b1, _Float16* __restrict__ C1,
    const _Float16* __restrict__ Bt2, const float* __restrict__ b2, _Float16* __restrict__ C2)
{
    __shared__ _Float16 Bs[2][128 * 64];   // 2 x 16 KB

    const int which = blockIdx.x >> 4;
    const int bn    = (blockIdx.x & 15) * 128;
    const int bm    = blockIdx.y * 64;

    const _Float16* Bt   = (which == 0) ? Bt0 : (which == 1) ? Bt1 : Bt2;
    const float*    bias = (which == 0) ? b0  : (which == 1) ? b1  : b2;
    _Float16*       C    = (which == 0) ? C0  : (which == 1) ? C1  : C2;

    const int tid  = threadIdx.x;
    const int lane = tid & 63;
    const int wv   = tid >> 6;          // 0..3
    const int wrow = wv >> 1;           // 0..1 -> rows 32*wrow
    const int wcol = wv & 1;            // 0..1 -> cols 64*wcol
    const int l31  = lane & 31;
    const int lk   = lane >> 5;         // 0..1 (k-half selector)
    const int RB   = blockIdx.y * 2 + wrow;   // row-block-of-32 (0..31)

    // B staging: wave wv covers rows [wv*32, wv*32+32), 4 x 1 KB per K-tile
    const _Float16* gB[4];
    int             lB[4];
    #pragma unroll
    for (int p = 0; p < 4; ++p) {
        const int r = wv * 32 + p * 8 + (lane >> 3);
        const int c = (lane & 7) ^ ((lane >> 3) & 7);
        gB[p] = Bt + (size_t)(bn + r) * DM + c * 8;
        lB[p] = (wv * 4 + p) * 512 + lane * 8;
    }

    f32x16 acc[2] = {};
    f16x8  aR[2][4];   // [set][ks]

    auto stageB = [&](int buf) {
        #pragma unroll
        for (int p = 0; p < 4; ++p) {
            __builtin_amdgcn_global_load_lds(
                (const __attribute__((address_space(1))) void*)gB[p],
                (__attribute__((address_space(3))) void*)&Bs[buf][lB[p]], 16, 0, 0);
            gB[p] += 64;
        }
    };
    auto loadA = [&](int rb, int kt) {
        const _Float16* base = A + ((size_t)RB * 128 + kt * 4) * 512 + lane * 8;
        #pragma unroll
        for (int ks = 0; ks < 4; ++ks)
            aR[rb][ks] = *(const f16x8*)(base + ks * 512);
    };
    auto compute = [&](int buf, int rb) {
        #pragma unroll
        for (int ks = 0; ks < 4; ++ks) {
            f16x8 bF[2];
            #pragma unroll
            for (int nt = 0; nt < 2; ++nt) {
                const int n = wcol * 64 + nt * 32 + l31;
                const int c = ks * 2 + lk;
                bF[nt] = *(const f16x8*)&Bs[buf][n * 64 + ((c ^ (n & 7)) << 3)];
            }
            #pragma unroll
            for (int nt = 0; nt < 2; ++nt)
                acc[nt] = __builtin_amdgcn_mfma_f32_32x32x16_f16(
                    aR[rb][ks], bF[nt], acc[nt], 0, 0, 0);
        }
    };

    stageB(0);
    loadA(0, 0);
    #pragma unroll 1
    for (int it2 = 0; it2 < 16; ++it2) {
        __syncthreads();                    // buf0 staged / prior buf0 reads done
        stageB(1);                          // tile 2*it2+1
        loadA(1, 2 * it2 + 1);
        compute(0, 0);                      // tile 2*it2
        __syncthreads();                    // buf1 staged / buf1 prior reads done
        if (it2 < 15) {
            stageB(0);                      // tile 2*it2+2
            loadA(0, 2 * it2 + 2);
        }
        compute(1, 1);                      // tile 2*it2+1
    }

    // epilogue: 32x32 C/D: col=lane&31, row=(reg&3)+8*(reg>>2)+4*(lane>>5)
    #pragma unroll
    for (int nt = 0; nt < 2; ++nt) {
        const int col = bn + wcol * 64 + nt * 32 + l31;
        const float bv = bias[col];
        const int rbase = bm + wrow * 32 + 4 * lk;
        #pragma unroll
        for (int r = 0; r < 16; ++r) {
            const int row = rbase + (r & 3) + 8 * (r >> 2);
            C[(size_t)row * DM + col] = (_Float16)(acc[nt][r] + bv);
        }
    }
}

// ---------------------------------------------------------------------------
// Double-buffered 16x16 MFMA GEMM (O-projection) — R7-verbatim
// (global_load_lds staging, static indices, bench-verified).
template<int WGR, int WGC, int WTR, int WTC, bool F16OUT>
__global__ __launch_bounds__(256, 3) void gemm_db(
    const _Float16* __restrict__ A,
    const _Float16* __restrict__ Bt0, const float* __restrict__ b0, void* __restrict__ C0,
    const _Float16* __restrict__ Bt1, const float* __restrict__ b1, void* __restrict__ C1,
    const _Float16* __restrict__ Bt2, const float* __restrict__ b2, void* __restrict__ C2)
{
    constexpr int BM  = WGR * WTR * 16;
    constexpr int BN  = WGC * WTC * 16;
    static_assert(BN == 128, "col tile must be 128");
    constexpr int NA  = BM / 8;
    constexpr int NB  = 16;
    constexpr int NC  = NA + NB;
    constexpr int CPW = NC / 4;
    static_assert(NC % 4 == 0);
    constexpr int BUF = (BM + 128) * 64;

    __shared__ _Float16 smem[2 * BUF];

    const int which = blockIdx.x >> 4;
    const int bn    = (blockIdx.x & 15) * 128;
    const int bm    = blockIdx.y * BM;

    const _Float16* Bt   = (which == 0) ? Bt0 : (which == 1) ? Bt1 : Bt2;
    const float*    bias = (which == 0) ? b0  : (which == 1) ? b1  : b2;
    void*           C    = (which == 0) ? C0  : (which == 1) ? C1  : C2;

    const int tid  = threadIdx.x;
    const int lane = tid & 63;
    const int wv   = tid >> 6;
    const int wr   = (wv / WGC) * (WTR * 16);
    const int wc   = (wv % WGC) * (WTC * 16);
    const int lr   = lane & 15;
    const int lk   = lane >> 4;
    const int rx   = lr & 7;

    const _Float16* gsrc[CPW];
    int             loff[CPW];
    #pragma unroll
    for (int p = 0; p < CPW; ++p) {
        const int c   = wv * CPW + p;
        const int kch = ((lane & 7) ^ (lane >> 3)) << 3;
        if (c < NA) {
            const int rl = c * 8 + (lane >> 3);
            gsrc[p] = A + (size_t)(bm + rl) * DM + kch;
            loff[p] = c * 512 + lane * 8;
        } else {
            const int rl = (c - NA) * 8 + (lane >> 3);
            gsrc[p] = Bt + (size_t)(bn + rl) * DM + kch;
            loff[p] = BM * 64 + (c - NA) * 512 + lane * 8;
        }
    }

    int offA[WTR][2], offB[WTC][2];
    #pragma unroll
    for (int ks = 0; ks < 2; ++ks) {
        const int sw = (((ks << 2) | lk) ^ rx) << 3;
        #pragma unroll
        for (int i = 0; i < WTR; ++i)
            offA[i][ks] = (wr + i * 16 + lr) * 64 + sw;
        #pragma unroll
        for (int j = 0; j < WTC; ++j)
            offB[j][ks] = BM * 64 + (wc + j * 16 + lr) * 64 + sw;
    }

    f32x4 acc[WTR][WTC] = {};

    auto prefetch = [&](int buf) {
        #pragma unroll
        for (int p = 0; p < CPW; ++p) {
            __builtin_amdgcn_global_load_lds(
                (const __attribute__((address_space(1))) void*)gsrc[p],
                (__attribute__((address_space(3))) void*)(smem + buf * BUF + loff[p]),
                16, 0, 0);
            gsrc[p] += 64;
        }
    };

    auto compute = [&](int buf) {
        const _Float16* base = smem + buf * BUF;
        #pragma unroll
        for (int ks = 0; ks < 2; ++ks) {
            f16x8 aF[WTR], bF[WTC];
            #pragma unroll
            for (int i = 0; i < WTR; ++i)
                aF[i] = *(const f16x8*)&base[offA[i][ks]];
            #pragma unroll
            for (int j = 0; j < WTC; ++j)
                bF[j] = *(const f16x8*)&base[offB[j][ks]];
            #pragma unroll
            for (int i = 0; i < WTR; ++i)
                #pragma unroll
                for (int j = 0; j < WTC; ++j)
                    acc[i][j] = __builtin_amdgcn_mfma_f32_16x16x32_f16(aF[i], bF[j], acc[i][j], 0, 0, 0);
        }
    };

    prefetch(0);
    #pragma unroll 1
    for (int it2 = 0; it2 < 16; ++it2) {
        __syncthreads();
        prefetch(1);
        compute(0);
        __syncthreads();
        if (it2 < 15) prefetch(0);
        compute(1);
    }

    #pragma unroll
    for (int i = 0; i < WTR; ++i) {
        #pragma unroll
        for (int j = 0; j < WTC; ++j) {
            const int col = bn + wc + j * 16 + lr;
            const float bv = bias[col];
            #pragma unroll
            for (int r = 0; r < 4; ++r) {
                const int row = bm + wr + i * 16 + lk * 4 + r;
                const float v = acc[i][j][r] + bv;
                if (F16OUT)
                    ((_Float16*)C)[(size_t)row * DM + col] = (_Float16)v;
                else
                    ((float*)C)[(size_t)row * DM + col] = v;
            }
        }
    }
}

// ---------------------------------------------------------------------------
// MFMA attention: one block per token, 4 waves, wave wv owns heads
// [64wv, 64wv+64). S^T = K.Q^T via mfma (K=8 zero-padded), exp in fp32,
// pack to fp16 in LDS (wave-private region, no barrier), O = A.V via mfma.
__global__ __launch_bounds__(256) void attn_mfma(
    const _Float16* __restrict__ Qh, const _Float16* __restrict__ Kh,
    const _Float16* __restrict__ Vh, _Float16* __restrict__ Oh)
{
    __shared__ _Float16 Vt[8][264];
    __shared__ _Float16 Al[256][72];
    __shared__ _Float16 Ot[256][8];

    const int t    = blockIdx.x;
    const int tid  = threadIdx.x;
    const int lane = tid & 63;
    const int wv   = tid >> 6;
    const int col  = lane & 15;
    const int quad = lane >> 4;
    const int hbase = wv * 64;

    const _Float16* qb = Qh + (size_t)t * DM;
    const _Float16* kb = Kh + (size_t)t * DM;
    const _Float16* vb = Vh + (size_t)t * DM;

    {
        const f16x8 v = *(const f16x8*)(vb + tid * 8);
        #pragma unroll
        for (int d = 0; d < 8; ++d) Vt[d][tid] = v[d];
    }

    f16x8 qf[4];
    #pragma unroll
    for (int ht = 0; ht < 4; ++ht) {
        f16x8 v = {};
        if (quad == 0)
            v = *(const f16x8*)(qb + (hbase + ht * 16 + col) * 8);
        #pragma unroll
        for (int j = 0; j < 8; ++j) qf[ht][j] = v[j] * (_Float16)SCALE;
    }

    __syncthreads();

    const f32x4 zf = {};
    float rsum[4] = {};
    f32x4 oacc[4] = {};

    #pragma unroll 1
    for (int c = 0; c < 4; ++c) {
        const int gchunk = c * 64;

        f16x8 kf[4];
        #pragma unroll
        for (int gt = 0; gt < 4; ++gt) {
            f16x8 v = {};
            if (quad == 0)
                v = *(const f16x8*)(kb + (gchunk + gt * 16 + col) * 8);
            kf[gt] = v;
        }

        f32x4 s[4][4];
        #pragma unroll
        for (int gt = 0; gt < 4; ++gt)
            #pragma unroll
            for (int ht = 0; ht < 4; ++ht)
                s[gt][ht] = __builtin_amdgcn_mfma_f32_16x16x32_f16(kf[gt], qf[ht], zf, 0, 0, 0);

        #pragma unroll
        for (int gt = 0; gt < 4; ++gt) {
            #pragma unroll
            for (int ht = 0; ht < 4; ++ht) {
                f16x4 e4;
                #pragma unroll
                for (int r = 0; r < 4; ++r) {
                    e4[r] = (_Float16)__expf(s[gt][ht][r]);
                    rsum[ht] += (float)e4[r];
                }
                *(f16x4*)&Al[hbase + ht * 16 + col][gt * 16 + quad * 4] = e4;
            }
        }

        #pragma unroll
        for (int ks = 0; ks < 2; ++ks) {
            f16x8 vf = {};
            if (col < 8)
                vf = *(const f16x8*)&Vt[col][gchunk + ks * 32 + quad * 8];
            #pragma unroll
            for (int ht = 0; ht < 4; ++ht) {
                const f16x8 af = *(const f16x8*)&Al[hbase + ht * 16 + col][ks * 32 + quad * 8];
                oacc[ht] = __builtin_amdgcn_mfma_f32_16x16x32_f16(af, vf, oacc[ht], 0, 0, 0);
            }
        }
    }

    #pragma unroll
    for (int ht = 0; ht < 4; ++ht) {
        rsum[ht] += __shfl_xor(rsum[ht], 16, 64);
        rsum[ht] += __shfl_xor(rsum[ht], 32, 64);
    }

    #pragma unroll
    for (int ht = 0; ht < 4; ++ht) {
        #pragma unroll
        for (int r = 0; r < 4; ++r) {
            const float sh = __shfl(rsum[ht], quad * 4 + r, 64);
            const float v  = oacc[ht][r] / sh;
            if (col < 8)
                Ot[hbase + ht * 16 + quad * 4 + r][col] = (_Float16)v;
        }
    }
    const f16x8 ov = *(const f16x8*)&Ot[tid][0];
    *(f16x8*)(Oh + (size_t)t * DM + tid * 8) = ov;
}

// ---------------------------------------------------------------------------
extern "C" void kernel_launch(void* const* d_in, const int* in_sizes, int n_in,
                              void* d_out, int out_size, void* d_ws, size_t ws_size,
                              hipStream_t stream)
{
    const float* x  = (const float*)d_in[0];
    // d_in[1] = phase_shift: cancels analytically (cos^2 + sin^2 = 1), unused
    const float* Wq = (const float*)d_in[2];
    const float* bq = (const float*)d_in[3];
    const float* Wk = (const float*)d_in[4];
    const float* bk = (const float*)d_in[5];
    const float* Wv = (const float*)d_in[6];
    const float* bv = (const float*)d_in[7];
    const float* Wo = (const float*)d_in[8];
    const float* bo = (const float*)d_in[9];
    float* out = (float*)d_out;

    char* ws = (char*)d_ws;
    _Float16* xa  = (_Float16*)(ws);                 // 4 MB, fragment-major
    _Float16* Wtq = (_Float16*)(ws + (4u  << 20));   // 8 MB
    _Float16* Wtk = (_Float16*)(ws + (12u << 20));   // 8 MB
    _Float16* Wtv = (_Float16*)(ws + (20u << 20));   // 8 MB
    _Float16* Wto = (_Float16*)(ws + (28u << 20));   // 8 MB
    _Float16* Qh  = (_Float16*)(ws + (36u << 20));   // 4 MB
    _Float16* Kh  = (_Float16*)(ws + (40u << 20));   // 4 MB
    _Float16* Vh  = (_Float16*)(ws + (44u << 20));   // 4 MB
    _Float16* Oh  = (_Float16*)(ws + (48u << 20));   // 4 MB

    prep<<<dim3(32, 32, 5), dim3(256), 0, stream>>>(
        x, xa, Wq, Wk, Wv, Wo, Wtq, Wtk, Wtv, Wto);

    // QKV fused: 64x128 tiles, 32x32x16 mfma, R7 staging, grid 48 x 16
    gemm_qkv32<<<dim3(48, 16), dim3(256), 0, stream>>>(xa,
        Wtq, bq, Qh,
        Wtk, bk, Kh,
        Wtv, bv, Vh);

    attn_mfma<<<dim3(M_TOK), dim3(256), 0, stream>>>(Qh, Kh, Vh, Oh);

    // output projection: 32x128 tiles, BK=64, R7 dbuf. grid 16 x 32
    gemm_db<1, 4, 2, 2, false><<<dim3(16, 32), dim3(256), 0, stream>>>(Oh,
        Wto, bo, (void*)out,
        Wto, bo, (void*)out,
        Wto, bo, (void*)out);
}